// Round 6
// baseline (42763.580 us; speedup 1.0000x reference)
//
#include <hip/hip_runtime.h>
#include <hip/hip_bf16.h>

// GRU: T=512, B=64, Cin=512, H=1024, 2 layers.
// Round 6: Little's-law fix. Round 5 measured 25 GB/s/CU coherent-read rate
// = 4KB in flight / 400cy L3 RTT. Quadruple in-flight: prefetch the ENTIRE
// per-wave K-half (16 pairs of 64B coherent loads) before the MFMA loop,
// countdown vmcnt. launch_bounds(512,2) to allow the 128 pipeline VGPRs.

#define Hh   1024
#define Bz   64
#define Tt   512
#define Mrows (Tt*Bz)   // 32768
#define NBLK 64

typedef __attribute__((ext_vector_type(8))) short short8;
typedef __attribute__((ext_vector_type(4))) float f32x4;
typedef __attribute__((ext_vector_type(4))) unsigned int u32x4;

__device__ __forceinline__ unsigned short f2bf(float f){
  unsigned u = __builtin_bit_cast(unsigned, f);
  u += 0x7fffu + ((u >> 16) & 1u);          // round-to-nearest-even
  return (unsigned short)(u >> 16);
}
__device__ __forceinline__ float bf2f(unsigned short s){
  unsigned u = ((unsigned)s) << 16;
  return __builtin_bit_cast(float, u);
}

// coherent stores (agent scope, relaxed)
__device__ __forceinline__ void cstore_u32(void* p, unsigned v){
  __hip_atomic_store((unsigned*)p, v, __ATOMIC_RELAXED, __HIP_MEMORY_SCOPE_AGENT);
}

__device__ __forceinline__ void gload16(const void* g, void* l){
  __builtin_amdgcn_global_load_lds(
      (const __attribute__((address_space(1))) unsigned int*)g,
      (__attribute__((address_space(3))) unsigned int*)l, 16, 0, 0);
}

// fence-free device barrier: monotonic counter, no reset, no cache flushes.
__device__ __forceinline__ void gbar(unsigned* bar, unsigned* bk){
  __syncthreads();
  *bk += 1;
  if (threadIdx.x == 0){
    __hip_atomic_fetch_add(bar, 1u, __ATOMIC_RELAXED, __HIP_MEMORY_SCOPE_AGENT);
    const unsigned tgt = (*bk) * NBLK;
    while (__hip_atomic_load(bar, __ATOMIC_RELAXED, __HIP_MEMORY_SCOPE_AGENT) < tgt)
      __builtin_amdgcn_s_sleep(1);
  }
  __syncthreads();
}

// ---- manually pipelined coherent loads ----
#define CLOAD16(dst, base, kk) \
  asm volatile("global_load_dwordx4 %0, %1, off offset:%c2 sc0 sc1" \
               : "=v"(dst) : "v"(base), "i"((kk)*64));
#define PLOADF(dst, addr) \
  asm volatile("global_load_dword %0, %1, off" : "=v"(dst) : "v"(addr));
#define PLOADU16(dst, addr) \
  asm volatile("global_load_ushort %0, %1, off" : "=v"(dst) : "v"(addr));
#define VMWAIT(n) \
  asm volatile("s_waitcnt vmcnt(%c0)" :: "i"(n) : "memory"); \
  __builtin_amdgcn_sched_barrier(0);

// ---------------- prep kernels ----------------

__global__ __launch_bounds__(256) void k_cvt_bf16(const float* __restrict__ src,
                                                  unsigned short* __restrict__ dst, int n4){
  int i = blockIdx.x*blockDim.x + threadIdx.x;
  int stride = gridDim.x*blockDim.x;
  for (; i < n4; i += stride){
    float4 v = reinterpret_cast<const float4*>(src)[i];
    ushort4 o; o.x=f2bf(v.x); o.y=f2bf(v.y); o.z=f2bf(v.z); o.w=f2bf(v.w);
    reinterpret_cast<ushort4*>(dst)[i] = o;
  }
}

// fp32 (K,N) -> bf16 (N,K), 64x64 LDS tile
__global__ __launch_bounds__(256) void k_transpose_bf16(const float* __restrict__ src,
                                                        unsigned short* __restrict__ dst,
                                                        int K, int N){
  __shared__ float tile[64][65];
  int k0 = blockIdx.x * 64, n0 = blockIdx.y * 64;
  int t = threadIdx.x;
  int r = t >> 4, c4 = (t & 15) << 2;
  #pragma unroll
  for (int j = 0; j < 4; ++j){
    const float4 v = *reinterpret_cast<const float4*>(&src[(size_t)(k0 + r + j*16) * N + n0 + c4]);
    tile[r+j*16][c4+0]=v.x; tile[r+j*16][c4+1]=v.y;
    tile[r+j*16][c4+2]=v.z; tile[r+j*16][c4+3]=v.w;
  }
  __syncthreads();
  #pragma unroll
  for (int j = 0; j < 4; ++j){
    int nn = r + j*16;
    ushort4 o;
    o.x = f2bf(tile[c4+0][nn]); o.y = f2bf(tile[c4+1][nn]);
    o.z = f2bf(tile[c4+2][nn]); o.w = f2bf(tile[c4+3][nn]);
    *reinterpret_cast<ushort4*>(&dst[(size_t)(n0+nn)*K + k0 + c4]) = o;
  }
}

__global__ void k_bias_fold(const float* __restrict__ a, const float* __restrict__ b,
                            const float* __restrict__ c, const float* __restrict__ d,
                            float* __restrict__ out){
  int i = blockIdx.x*blockDim.x + threadIdx.x;
  if (i < 2048) out[i] = a[i] + b[i];
  else if (i < 3072) out[i] = c[i-2048] + d[i-2048];
}

// ---------------- big x-projection GEMM ----------------
__global__ __launch_bounds__(256) void k_xproj_gemm(
    const unsigned short* __restrict__ A, const unsigned short* __restrict__ Bt,
    const float* __restrict__ bias, unsigned short* __restrict__ outRZ,
    float* __restrict__ outC, int K)
{
  __shared__ __align__(16) unsigned short As[128*32];
  __shared__ __align__(16) unsigned short Bs[128*32];
  const int nb = blockIdx.x, mb = blockIdx.y;
  const int m0 = mb*128, n0 = nb*128;
  const int t = threadIdx.x, lane = t & 63, w = t >> 6;
  const int wr = w >> 1, wc = w & 1;
  const int lr = lane & 15, lq = lane >> 4;
  const int sr = t >> 2, scg = t & 3;
  f32x4 acc[4][4];
  const f32x4 zero4 = {0.f,0.f,0.f,0.f};
  #pragma unroll
  for (int mt=0;mt<4;++mt)
    #pragma unroll
    for (int nt=0;nt<4;++nt) acc[mt][nt] = zero4;

  const unsigned short* ga0 = &A [(size_t)(m0 + sr     )*K + scg*8];
  const unsigned short* ga1 = &A [(size_t)(m0 + sr + 64)*K + scg*8];
  const unsigned short* gb0 = &Bt[(size_t)(n0 + sr     )*K + scg*8];
  const unsigned short* gb1 = &Bt[(size_t)(n0 + sr + 64)*K + scg*8];
  char* lA = (char*)As + w*1024;
  char* lB = (char*)Bs + w*1024;
  const int kiters = K >> 5;
  for (int kt = 0; kt < kiters; ++kt){
    __syncthreads();
    gload16(ga0 + kt*32, lA);
    gload16(ga1 + kt*32, lA + 4096);
    gload16(gb0 + kt*32, lB);
    gload16(gb1 + kt*32, lB + 4096);
    asm volatile("s_waitcnt vmcnt(0)" ::: "memory");
    __syncthreads();
    short8 af[4], bfr[4];
    #pragma unroll
    for (int mt=0; mt<4; ++mt)
      af[mt] = *reinterpret_cast<const short8*>(&As[(wr*64 + mt*16 + lr)*32 + lq*8]);
    #pragma unroll
    for (int nt=0; nt<4; ++nt)
      bfr[nt] = *reinterpret_cast<const short8*>(&Bs[(wc*64 + nt*16 + lr)*32 + lq*8]);
    #pragma unroll
    for (int mt=0; mt<4; ++mt)
      #pragma unroll
      for (int nt=0; nt<4; ++nt)
        acc[mt][nt] = __builtin_amdgcn_mfma_f32_16x16x32_bf16(af[mt], bfr[nt], acc[mt][nt], 0,0,0);
  }
  const bool isRZ = (n0 < 2048);
  #pragma unroll
  for (int mt=0;mt<4;++mt){
    #pragma unroll
    for (int nt=0;nt<4;++nt){
      int gn = n0 + wc*64 + nt*16 + lr;
      float bv = bias[gn];
      #pragma unroll
      for (int i=0;i<4;++i){
        int gm = m0 + wr*64 + mt*16 + lq*4 + i;
        float v = acc[mt][nt][i] + bv;
        if (isRZ) outRZ[(size_t)gm*2048 + gn] = f2bf(v);
        else      outC [(size_t)gm*1024 + (gn - 2048)] = v;
      }
    }
  }
}

// ---------------- persistent per-layer recurrent kernel ----------------
// 64 blocks x 512 threads (1 block/CU). Block b owns cols [16b,16b+16) of
// r, z, cand, h. Waves = (m-tile 0-3) x (K-half 0-1), LDS partial combine.
// Cross-block state: only a(hi/lo) and h(hi/lo) bf16, via coherent ld/st.
__global__ __launch_bounds__(512, 2) void k_gru_layer(
    const unsigned short* __restrict__ Wrzg,   // (2048,1024) bf16
    const unsigned short* __restrict__ Whhg,   // (1024,1024) bf16
    const unsigned short* __restrict__ XprojRZ,// (T,64,2048) bf16, biases folded
    const float* __restrict__ XprojC,          // (T,64,1024) fp32, biases folded
    unsigned short* hhi, unsigned short* hlo,
    unsigned short* abhi, unsigned short* ablo,
    unsigned short* __restrict__ h0seq,        // L0: bf16 sequence out (else null)
    float* __restrict__ outseq,                // L1: fp32 sequence out (else null)
    float* __restrict__ hn,                    // final h slot
    unsigned* bar)
{
  __shared__ __align__(16) unsigned short WrzS[32*1024]; // 64KB rows0-15=r,16-31=z
  __shared__ __align__(16) unsigned short WhhS[16*1024]; // 32KB
  __shared__ float hloc[64][17];                         // block's fp32 h slice
  __shared__ float zloc[64][17];                         // block's z slice
  __shared__ float partial[4][64][9];                    // K-split combine

  const int b   = blockIdx.x;
  const int tid = threadIdx.x;
  const int lane = tid & 63, w = tid >> 6;
  const int lr = lane & 15, lq = lane >> 4;
  unsigned bk = 0;

  // ---- stage weights into LDS (once), XOR-swizzled ----
  #pragma unroll
  for (int j = 0; j < 8; ++j){
    int lin = (tid + j*512) * 8;
    int n = lin >> 10, k = lin & 1023;
    int gr = (n < 16) ? (16*b + n) : (1024 + 16*b + (n - 16));
    short8 v = *reinterpret_cast<const short8*>(&Wrzg[(size_t)gr*1024 + k]);
    *reinterpret_cast<short8*>(&WrzS[(n*1024 + k) ^ ((n&7)<<3)]) = v;
  }
  #pragma unroll
  for (int j = 0; j < 4; ++j){
    int lin = (tid + j*512) * 8;
    int n = lin >> 10, k = lin & 1023;
    short8 v = *reinterpret_cast<const short8*>(&Whhg[(size_t)(16*b + n)*1024 + k]);
    *reinterpret_cast<short8*>(&WhhS[(n*1024 + k) ^ ((n&7)<<3)]) = v;
  }
  // ---- zero local h and the global h broadcast slice (ws is poisoned) ----
  for (int idx = tid; idx < 64*17; idx += 512) ((float*)hloc)[idx] = 0.f;
  {
    int r = tid >> 3, cp = (tid & 7) * 2;
    cstore_u32(&hhi[r*1024 + 16*b + cp], 0u);
    cstore_u32(&hlo[r*1024 + 16*b + cp], 0u);
  }
  gbar(bar, &bk);

  const int mt = w & 3, kh = w >> 2;   // wave = (m-tile, K-half) in both phases
  const int rA = 16*mt;                // batch-row tile base
  const int kb = kh*512;               // K-half base

  for (int t = 0; t < Tt; ++t){
    // ================= phase A: rz preact + gates =================
    {
      const unsigned short* xp = XprojRZ + (size_t)t*Bz*2048;
      // epilogue loads issued FIRST (vmcnt in-order: retired before pair 0)
      unsigned xr[4], xz[4];
      #pragma unroll
      for (int i = 0; i < 4; ++i){
        PLOADU16(xr[i], &xp[(rA + lq*4 + i)*2048 + 16*b + lr]);
        PLOADU16(xz[i], &xp[(rA + lq*4 + i)*2048 + 1024 + 16*b + lr]);
      }
      const unsigned short* hhp = hhi + (rA + lr)*1024 + kb + lq*8;
      const unsigned short* hlp = hlo + (rA + lr)*1024 + kb + lq*8;
      u32x4 ahv[16], alv[16];
      #pragma unroll
      for (int s = 0; s < 16; ++s){ CLOAD16(ahv[s], hhp, s) CLOAD16(alv[s], hlp, s) }
      f32x4 accr0={0,0,0,0}, accr1={0,0,0,0}, accz0={0,0,0,0}, accz1={0,0,0,0};
      #pragma unroll
      for (int k = 0; k < 16; ++k){
        VMWAIT(30 - 2*k)
        short8 ah = __builtin_bit_cast(short8, ahv[k]);
        short8 al = __builtin_bit_cast(short8, alv[k]);
        short8 br = *reinterpret_cast<const short8*>(
            &WrzS[(lr*1024 + kb + k*32 + lq*8) ^ ((lr&7)<<3)]);
        short8 bz = *reinterpret_cast<const short8*>(
            &WrzS[((16+lr)*1024 + kb + k*32 + lq*8) ^ ((lr&7)<<3)]);
        accr0 = __builtin_amdgcn_mfma_f32_16x16x32_bf16(ah, br, accr0, 0,0,0);
        accr1 = __builtin_amdgcn_mfma_f32_16x16x32_bf16(al, br, accr1, 0,0,0);
        accz0 = __builtin_amdgcn_mfma_f32_16x16x32_bf16(ah, bz, accz0, 0,0,0);
        accz1 = __builtin_amdgcn_mfma_f32_16x16x32_bf16(al, bz, accz1, 0,0,0);
      }
      f32x4 accr = accr0 + accr1, accz = accz0 + accz1;
      if (kh == 1){
        #pragma unroll
        for (int i = 0; i < 4; ++i){
          partial[mt][lane][i]   = accr[i];
          partial[mt][lane][4+i] = accz[i];
        }
      }
      __syncthreads();
      if (kh == 0){
        #pragma unroll
        for (int i = 0; i < 4; ++i){
          int row = rA + lq*4 + i;
          float pr = accr[i] + partial[mt][lane][i]   + bf2f((unsigned short)xr[i]);
          float pz = accz[i] + partial[mt][lane][4+i] + bf2f((unsigned short)xz[i]);
          float rg = 1.f / (1.f + __expf(-pr));
          float zg = 1.f / (1.f + __expf(-pz));
          zloc[row][lr] = zg;
          float av = hloc[row][lr] * rg;
          unsigned short hi = f2bf(av);
          unsigned short lo = f2bf(av - bf2f(hi));
          unsigned hi2 = (unsigned)__shfl_down((int)hi, 1) & 0xffffu;
          unsigned lo2 = (unsigned)__shfl_down((int)lo, 1) & 0xffffu;
          if (!(lane & 1)){
            cstore_u32(&abhi[row*1024 + 16*b + lr], (unsigned)hi | (hi2<<16));
            cstore_u32(&ablo[row*1024 + 16*b + lr], (unsigned)lo | (lo2<<16));
          }
        }
      }
    }
    gbar(bar, &bk);
    // ================= phase B: cand + state update =================
    {
      const float* xc_t = XprojC + (size_t)t*Bz*1024;
      float xcv[4];
      if (kh == 0){
        #pragma unroll
        for (int i = 0; i < 4; ++i)
          PLOADF(xcv[i], &xc_t[(rA + lq*4 + i)*1024 + 16*b + lr]);
      }
      const unsigned short* ahp = abhi + (rA + lr)*1024 + kb + lq*8;
      const unsigned short* alp = ablo + (rA + lr)*1024 + kb + lq*8;
      u32x4 ahv[16], alv[16];
      #pragma unroll
      for (int s = 0; s < 16; ++s){ CLOAD16(ahv[s], ahp, s) CLOAD16(alv[s], alp, s) }
      f32x4 acc0={0,0,0,0}, acc1={0,0,0,0};
      #pragma unroll
      for (int k = 0; k < 16; ++k){
        VMWAIT(30 - 2*k)
        short8 ah = __builtin_bit_cast(short8, ahv[k]);
        short8 al = __builtin_bit_cast(short8, alv[k]);
        short8 bb = *reinterpret_cast<const short8*>(
            &WhhS[(lr*1024 + kb + k*32 + lq*8) ^ ((lr&7)<<3)]);
        acc0 = __builtin_amdgcn_mfma_f32_16x16x32_bf16(ah, bb, acc0, 0,0,0);
        acc1 = __builtin_amdgcn_mfma_f32_16x16x32_bf16(al, bb, acc1, 0,0,0);
      }
      f32x4 acc = acc0 + acc1;
      if (kh == 1){
        #pragma unroll
        for (int i = 0; i < 4; ++i) partial[mt][lane][i] = acc[i];
      }
      __syncthreads();
      if (kh == 0){
        #pragma unroll
        for (int i = 0; i < 4; ++i){
          int row = rA + lq*4 + i;
          int col = 16*b + lr;
          float pre = acc[i] + partial[mt][lane][i] + xcv[i];
          float cand = tanhf(pre);
          float zg = zloc[row][lr];
          float h  = hloc[row][lr];
          float hnew = zg*h + (1.f - zg)*cand;
          hloc[row][lr] = hnew;
          unsigned short hi = f2bf(hnew);
          unsigned short lo = f2bf(hnew - bf2f(hi));
          unsigned hi2 = (unsigned)__shfl_down((int)hi, 1) & 0xffffu;
          unsigned lo2 = (unsigned)__shfl_down((int)lo, 1) & 0xffffu;
          if (!(lane & 1)){
            cstore_u32(&hhi[row*1024 + col], (unsigned)hi | (hi2<<16));
            cstore_u32(&hlo[row*1024 + col], (unsigned)lo | (lo2<<16));
          }
          if (h0seq)  h0seq [(size_t)t*(Bz*Hh) + row*1024 + col] = hi;
          if (outseq) outseq[(size_t)t*(Bz*Hh) + row*1024 + col] = hnew;
          if (t == Tt-1) hn[row*1024 + col] = hnew;
        }
      }
    }
    gbar(bar, &bk);
  }
}

// ---------------- host ----------------

extern "C" void kernel_launch(void* const* d_in, const int* in_sizes, int n_in,
                              void* d_out, int out_size, void* d_ws, size_t ws_size,
                              hipStream_t stream)
{
  (void)in_sizes; (void)n_in; (void)out_size; (void)ws_size;
  const float* X     = (const float*)d_in[0];
  const float* Wxrz0 = (const float*)d_in[1];
  const float* bxrz0 = (const float*)d_in[2];
  const float* Whrz0 = (const float*)d_in[3];
  const float* bhrz0 = (const float*)d_in[4];
  const float* Wxh0  = (const float*)d_in[5];
  const float* bxh0  = (const float*)d_in[6];
  const float* Whh0  = (const float*)d_in[7];
  const float* bhh0  = (const float*)d_in[8];
  const float* Wxrz1 = (const float*)d_in[9];
  const float* bxrz1 = (const float*)d_in[10];
  const float* Whrz1 = (const float*)d_in[11];
  const float* bhrz1 = (const float*)d_in[12];
  const float* Wxh1  = (const float*)d_in[13];
  const float* bxh1  = (const float*)d_in[14];
  const float* Whh1  = (const float*)d_in[15];
  const float* bhh1  = (const float*)d_in[16];

  char* p = (char*)d_ws;
  auto carve = [&](size_t bytes)->char*{
    char* r = p; p += (bytes + 255) & ~(size_t)255; return r;
  };
  unsigned short* Xbf    = (unsigned short*)carve((size_t)Mrows*512*2);
  unsigned short* W0t    = (unsigned short*)carve((size_t)3072*512*2);
  unsigned short* W1t    = (unsigned short*)carve((size_t)3072*1024*2);
  unsigned short* Whrz0t = (unsigned short*)carve((size_t)2048*1024*2);
  unsigned short* Whh0t  = (unsigned short*)carve((size_t)1024*1024*2);
  unsigned short* Whrz1t = (unsigned short*)carve((size_t)2048*1024*2);
  unsigned short* Whh1t  = (unsigned short*)carve((size_t)1024*1024*2);
  float* bias0 = (float*)carve(3072*4);
  float* bias1 = (float*)carve(3072*4);
  unsigned short* XprojRZ = (unsigned short*)carve((size_t)Mrows*2048*2);
  float*          XprojC  = (float*)carve((size_t)Mrows*1024*4);
  unsigned short* H0seq   = (unsigned short*)carve((size_t)Mrows*1024*2);
  unsigned short* hhi  = (unsigned short*)carve(Bz*Hh*2);
  unsigned short* hlo  = (unsigned short*)carve(Bz*Hh*2);
  unsigned short* abhi = (unsigned short*)carve(Bz*Hh*2);
  unsigned short* ablo = (unsigned short*)carve(Bz*Hh*2);
  unsigned* bar = (unsigned*)carve(512);

  hipMemsetAsync(bar, 0, 512, stream);

  k_cvt_bf16<<<2048,256,0,stream>>>(X, Xbf, Mrows*512/4);
  k_transpose_bf16<<<dim3(8,32), 256,0,stream>>>(Wxrz0, W0t, 512, 2048);
  k_transpose_bf16<<<dim3(8,16), 256,0,stream>>>(Wxh0,  W0t + (size_t)2048*512, 512, 1024);
  k_transpose_bf16<<<dim3(16,32),256,0,stream>>>(Whrz0, Whrz0t, 1024, 2048);
  k_transpose_bf16<<<dim3(16,16),256,0,stream>>>(Whh0,  Whh0t, 1024, 1024);
  k_transpose_bf16<<<dim3(16,32),256,0,stream>>>(Wxrz1, W1t, 1024, 2048);
  k_transpose_bf16<<<dim3(16,16),256,0,stream>>>(Wxh1,  W1t + (size_t)2048*1024, 1024, 1024);
  k_transpose_bf16<<<dim3(16,32),256,0,stream>>>(Whrz1, Whrz1t, 1024, 2048);
  k_transpose_bf16<<<dim3(16,16),256,0,stream>>>(Whh1,  Whh1t, 1024, 1024);
  k_bias_fold<<<12,256,0,stream>>>(bxrz0, bhrz0, bxh0, bhh0, bias0);
  k_bias_fold<<<12,256,0,stream>>>(bxrz1, bhrz1, bxh1, bhh1, bias1);

  float* out = (float*)d_out;
  float* hn0 = out + (size_t)Mrows*Hh;
  float* hn1 = hn0 + Bz*Hh;

  // ---- layer 0 ----
  k_xproj_gemm<<<dim3(24,256),256,0,stream>>>(Xbf, W0t, bias0, XprojRZ, XprojC, 512);
  k_gru_layer<<<NBLK,512,0,stream>>>(Whrz0t, Whh0t, XprojRZ, XprojC,
                                     hhi, hlo, abhi, ablo,
                                     H0seq, nullptr, hn0, bar);
  // ---- layer 1 ----
  k_xproj_gemm<<<dim3(24,256),256,0,stream>>>(H0seq, W1t, bias1, XprojRZ, XprojC, 1024);
  k_gru_layer<<<NBLK,512,0,stream>>>(Whrz1t, Whh1t, XprojRZ, XprojC,
                                     hhi, hlo, abhi, ablo,
                                     nullptr, out, hn1, bar + 64);
}

// Round 7
// 27851.010 us; speedup vs baseline: 1.5354x; 1.5354x over previous
//
#include <hip/hip_runtime.h>
#include <hip/hip_bf16.h>

// GRU: T=512, B=64, Cin=512, H=1024, 2 layers.
// Round 7: cached-load coherence. Rounds 5/6 showed sc0sc1 (L2-bypass) reads
// are capped by per-CU line-parallelism x L3 RTT (~25 GB/s/CU) and deeper
// bursts only congest. Switch h/a reads to PLAIN cached loads; correctness
// via acquire-fence (L1+L2 invalidate, no writeback) after each global
// barrier -- all cross-step stores are write-through so L2 is never dirty.
// Round 2 proved this coherence pattern correct and the fence cheap.

#define Hh   1024
#define Bz   64
#define Tt   512
#define Mrows (Tt*Bz)   // 32768
#define NBLK 64

typedef __attribute__((ext_vector_type(8))) short short8;
typedef __attribute__((ext_vector_type(4))) float f32x4;
typedef __attribute__((ext_vector_type(4))) unsigned int u32x4;

__device__ __forceinline__ unsigned short f2bf(float f){
  unsigned u = __builtin_bit_cast(unsigned, f);
  u += 0x7fffu + ((u >> 16) & 1u);          // round-to-nearest-even
  return (unsigned short)(u >> 16);
}
__device__ __forceinline__ float bf2f(unsigned short s){
  unsigned u = ((unsigned)s) << 16;
  return __builtin_bit_cast(float, u);
}

// write-through stores (agent scope, relaxed): visible at L3 on vmcnt retire,
// never leave dirty L2 lines (safe to invalidate).
__device__ __forceinline__ void cstore_u32(void* p, unsigned v){
  __hip_atomic_store((unsigned*)p, v, __ATOMIC_RELAXED, __HIP_MEMORY_SCOPE_AGENT);
}
__device__ __forceinline__ void cstore_f32(float* p, float v){
  __hip_atomic_store(p, v, __ATOMIC_RELAXED, __HIP_MEMORY_SCOPE_AGENT);
}

__device__ __forceinline__ void gload16(const void* g, void* l){
  __builtin_amdgcn_global_load_lds(
      (const __attribute__((address_space(1))) unsigned int*)g,
      (__attribute__((address_space(3))) unsigned int*)l, 16, 0, 0);
}

// fence-free device barrier: monotonic counter, no reset.
__device__ __forceinline__ void gbar(unsigned* bar, unsigned* bk){
  __syncthreads();
  *bk += 1;
  if (threadIdx.x == 0){
    __hip_atomic_fetch_add(bar, 1u, __ATOMIC_RELAXED, __HIP_MEMORY_SCOPE_AGENT);
    const unsigned tgt = (*bk) * NBLK;
    while (__hip_atomic_load(bar, __ATOMIC_RELAXED, __HIP_MEMORY_SCOPE_AGENT) < tgt)
      __builtin_amdgcn_s_sleep(1);
  }
  __syncthreads();
}

// ---- manually pipelined loads (plain/cached) ----
#define PLOAD16(dst, base, kk) \
  asm volatile("global_load_dwordx4 %0, %1, off offset:%c2" \
               : "=v"(dst) : "v"(base), "i"((kk)*64));
#define PLOADF(dst, addr) \
  asm volatile("global_load_dword %0, %1, off" : "=v"(dst) : "v"(addr));
#define PLOADU16(dst, addr) \
  asm volatile("global_load_ushort %0, %1, off" : "=v"(dst) : "v"(addr));
#define VMWAIT(n) \
  asm volatile("s_waitcnt vmcnt(%c0)" :: "i"(n) : "memory"); \
  __builtin_amdgcn_sched_barrier(0);

// ---------------- prep kernels ----------------

__global__ __launch_bounds__(256) void k_cvt_bf16(const float* __restrict__ src,
                                                  unsigned short* __restrict__ dst, int n4){
  int i = blockIdx.x*blockDim.x + threadIdx.x;
  int stride = gridDim.x*blockDim.x;
  for (; i < n4; i += stride){
    float4 v = reinterpret_cast<const float4*>(src)[i];
    ushort4 o; o.x=f2bf(v.x); o.y=f2bf(v.y); o.z=f2bf(v.z); o.w=f2bf(v.w);
    reinterpret_cast<ushort4*>(dst)[i] = o;
  }
}

// fp32 (K,N) -> bf16 (N,K), 64x64 LDS tile
__global__ __launch_bounds__(256) void k_transpose_bf16(const float* __restrict__ src,
                                                        unsigned short* __restrict__ dst,
                                                        int K, int N){
  __shared__ float tile[64][65];
  int k0 = blockIdx.x * 64, n0 = blockIdx.y * 64;
  int t = threadIdx.x;
  int r = t >> 4, c4 = (t & 15) << 2;
  #pragma unroll
  for (int j = 0; j < 4; ++j){
    const float4 v = *reinterpret_cast<const float4*>(&src[(size_t)(k0 + r + j*16) * N + n0 + c4]);
    tile[r+j*16][c4+0]=v.x; tile[r+j*16][c4+1]=v.y;
    tile[r+j*16][c4+2]=v.z; tile[r+j*16][c4+3]=v.w;
  }
  __syncthreads();
  #pragma unroll
  for (int j = 0; j < 4; ++j){
    int nn = r + j*16;
    ushort4 o;
    o.x = f2bf(tile[c4+0][nn]); o.y = f2bf(tile[c4+1][nn]);
    o.z = f2bf(tile[c4+2][nn]); o.w = f2bf(tile[c4+3][nn]);
    *reinterpret_cast<ushort4*>(&dst[(size_t)(n0+nn)*K + k0 + c4]) = o;
  }
}

__global__ void k_bias_fold(const float* __restrict__ a, const float* __restrict__ b,
                            const float* __restrict__ c, const float* __restrict__ d,
                            float* __restrict__ out){
  int i = blockIdx.x*blockDim.x + threadIdx.x;
  if (i < 2048) out[i] = a[i] + b[i];
  else if (i < 3072) out[i] = c[i-2048] + d[i-2048];
}

// ---------------- big x-projection GEMM ----------------
__global__ __launch_bounds__(256) void k_xproj_gemm(
    const unsigned short* __restrict__ A, const unsigned short* __restrict__ Bt,
    const float* __restrict__ bias, unsigned short* __restrict__ outRZ,
    float* __restrict__ outC, int K)
{
  __shared__ __align__(16) unsigned short As[128*32];
  __shared__ __align__(16) unsigned short Bs[128*32];
  const int nb = blockIdx.x, mb = blockIdx.y;
  const int m0 = mb*128, n0 = nb*128;
  const int t = threadIdx.x, lane = t & 63, w = t >> 6;
  const int wr = w >> 1, wc = w & 1;
  const int lr = lane & 15, lq = lane >> 4;
  const int sr = t >> 2, scg = t & 3;
  f32x4 acc[4][4];
  const f32x4 zero4 = {0.f,0.f,0.f,0.f};
  #pragma unroll
  for (int mt=0;mt<4;++mt)
    #pragma unroll
    for (int nt=0;nt<4;++nt) acc[mt][nt] = zero4;

  const unsigned short* ga0 = &A [(size_t)(m0 + sr     )*K + scg*8];
  const unsigned short* ga1 = &A [(size_t)(m0 + sr + 64)*K + scg*8];
  const unsigned short* gb0 = &Bt[(size_t)(n0 + sr     )*K + scg*8];
  const unsigned short* gb1 = &Bt[(size_t)(n0 + sr + 64)*K + scg*8];
  char* lA = (char*)As + w*1024;
  char* lB = (char*)Bs + w*1024;
  const int kiters = K >> 5;
  for (int kt = 0; kt < kiters; ++kt){
    __syncthreads();
    gload16(ga0 + kt*32, lA);
    gload16(ga1 + kt*32, lA + 4096);
    gload16(gb0 + kt*32, lB);
    gload16(gb1 + kt*32, lB + 4096);
    asm volatile("s_waitcnt vmcnt(0)" ::: "memory");
    __syncthreads();
    short8 af[4], bfr[4];
    #pragma unroll
    for (int mt=0; mt<4; ++mt)
      af[mt] = *reinterpret_cast<const short8*>(&As[(wr*64 + mt*16 + lr)*32 + lq*8]);
    #pragma unroll
    for (int nt=0; nt<4; ++nt)
      bfr[nt] = *reinterpret_cast<const short8*>(&Bs[(wc*64 + nt*16 + lr)*32 + lq*8]);
    #pragma unroll
    for (int mt=0; mt<4; ++mt)
      #pragma unroll
      for (int nt=0; nt<4; ++nt)
        acc[mt][nt] = __builtin_amdgcn_mfma_f32_16x16x32_bf16(af[mt], bfr[nt], acc[mt][nt], 0,0,0);
  }
  const bool isRZ = (n0 < 2048);
  #pragma unroll
  for (int mt=0;mt<4;++mt){
    #pragma unroll
    for (int nt=0;nt<4;++nt){
      int gn = n0 + wc*64 + nt*16 + lr;
      float bv = bias[gn];
      #pragma unroll
      for (int i=0;i<4;++i){
        int gm = m0 + wr*64 + mt*16 + lq*4 + i;
        float v = acc[mt][nt][i] + bv;
        if (isRZ) outRZ[(size_t)gm*2048 + gn] = f2bf(v);
        else      outC [(size_t)gm*1024 + (gn - 2048)] = v;
      }
    }
  }
}

// ---------------- persistent per-layer recurrent kernel ----------------
// 64 blocks x 512 threads (1 block/CU). Block b owns cols [16b,16b+16) of
// r, z, cand, h. Waves = (m-tile 0-3) x (K-half 0-1), LDS partial combine.
// Cross-block state (h, a): write-through stores + cached reads, made
// coherent by an agent-scope ACQUIRE fence (cache invalidate) per phase.
__global__ __launch_bounds__(512) void k_gru_layer(
    const unsigned short* __restrict__ Wrzg,   // (2048,1024) bf16
    const unsigned short* __restrict__ Whhg,   // (1024,1024) bf16
    const unsigned short* __restrict__ XprojRZ,// (T,64,2048) bf16, biases folded
    const float* __restrict__ XprojC,          // (T,64,1024) fp32, biases folded
    unsigned short* hhi, unsigned short* hlo,
    unsigned short* abhi, unsigned short* ablo,
    unsigned short* __restrict__ h0seq,        // L0: bf16 sequence out (else null)
    float* __restrict__ outseq,                // L1: fp32 sequence out (else null)
    float* __restrict__ hn,                    // final h slot
    unsigned* bar)
{
  __shared__ __align__(16) unsigned short WrzS[32*1024]; // 64KB rows0-15=r,16-31=z
  __shared__ __align__(16) unsigned short WhhS[16*1024]; // 32KB
  __shared__ float hloc[64][17];                         // block's fp32 h slice
  __shared__ float zloc[64][17];                         // block's z slice
  __shared__ float partial[4][64][9];                    // K-split combine

  const int b   = blockIdx.x;
  const int tid = threadIdx.x;
  const int lane = tid & 63, w = tid >> 6;
  const int lr = lane & 15, lq = lane >> 4;
  unsigned bk = 0;

  // ---- stage weights into LDS (once), XOR-swizzled ----
  #pragma unroll
  for (int j = 0; j < 8; ++j){
    int lin = (tid + j*512) * 8;
    int n = lin >> 10, k = lin & 1023;
    int gr = (n < 16) ? (16*b + n) : (1024 + 16*b + (n - 16));
    short8 v = *reinterpret_cast<const short8*>(&Wrzg[(size_t)gr*1024 + k]);
    *reinterpret_cast<short8*>(&WrzS[(n*1024 + k) ^ ((n&7)<<3)]) = v;
  }
  #pragma unroll
  for (int j = 0; j < 4; ++j){
    int lin = (tid + j*512) * 8;
    int n = lin >> 10, k = lin & 1023;
    short8 v = *reinterpret_cast<const short8*>(&Whhg[(size_t)(16*b + n)*1024 + k]);
    *reinterpret_cast<short8*>(&WhhS[(n*1024 + k) ^ ((n&7)<<3)]) = v;
  }
  // ---- zero local h and the global h broadcast slice (ws is poisoned) ----
  for (int idx = tid; idx < 64*17; idx += 512) ((float*)hloc)[idx] = 0.f;
  {
    int r = tid >> 3, cp = (tid & 7) * 2;
    cstore_u32(&hhi[r*1024 + 16*b + cp], 0u);
    cstore_u32(&hlo[r*1024 + 16*b + cp], 0u);
  }
  gbar(bar, &bk);

  const int mt = w & 3, kh = w >> 2;   // wave = (m-tile, K-half) in both phases
  const int rA = 16*mt;                // batch-row tile base
  const int kb = kh*512;               // K-half base

  for (int t = 0; t < Tt; ++t){
    // ================= phase A: rz preact + gates =================
    {
      // drop stale h lines (L1+L2 invalidate, no writeback; L2 never dirty)
      __builtin_amdgcn_fence(__ATOMIC_ACQUIRE, "agent");
      const unsigned short* xp = XprojRZ + (size_t)t*Bz*2048;
      // epilogue scalars issued FIRST (vmcnt is in-order: retired before pair 0)
      unsigned xr[4], xz[4];
      #pragma unroll
      for (int i = 0; i < 4; ++i){
        PLOADU16(xr[i], &xp[(rA + lq*4 + i)*2048 + 16*b + lr]);
        PLOADU16(xz[i], &xp[(rA + lq*4 + i)*2048 + 1024 + 16*b + lr]);
      }
      const unsigned short* hhp = hhi + (rA + lr)*1024 + kb + lq*8;
      const unsigned short* hlp = hlo + (rA + lr)*1024 + kb + lq*8;
      u32x4 ahv[8], alv[8];
      #pragma unroll
      for (int s = 0; s < 8; ++s){ PLOAD16(ahv[s], hhp, s) PLOAD16(alv[s], hlp, s) }
      f32x4 accr0={0,0,0,0}, accr1={0,0,0,0}, accz0={0,0,0,0}, accz1={0,0,0,0};
      #pragma unroll
      for (int k = 0; k < 16; ++k){
        const int slot = k & 7;
        VMWAIT(k < 8 ? 14 : 30 - 2*k)
        short8 ah = __builtin_bit_cast(short8, ahv[slot]);
        short8 al = __builtin_bit_cast(short8, alv[slot]);
        short8 br = *reinterpret_cast<const short8*>(
            &WrzS[(lr*1024 + kb + k*32 + lq*8) ^ ((lr&7)<<3)]);
        short8 bz = *reinterpret_cast<const short8*>(
            &WrzS[((16+lr)*1024 + kb + k*32 + lq*8) ^ ((lr&7)<<3)]);
        accr0 = __builtin_amdgcn_mfma_f32_16x16x32_bf16(ah, br, accr0, 0,0,0);
        accr1 = __builtin_amdgcn_mfma_f32_16x16x32_bf16(al, br, accr1, 0,0,0);
        accz0 = __builtin_amdgcn_mfma_f32_16x16x32_bf16(ah, bz, accz0, 0,0,0);
        accz1 = __builtin_amdgcn_mfma_f32_16x16x32_bf16(al, bz, accz1, 0,0,0);
        if (k < 8){ PLOAD16(ahv[slot], hhp, k+8) PLOAD16(alv[slot], hlp, k+8) }
      }
      f32x4 accr = accr0 + accr1, accz = accz0 + accz1;
      if (kh == 1){
        #pragma unroll
        for (int i = 0; i < 4; ++i){
          partial[mt][lane][i]   = accr[i];
          partial[mt][lane][4+i] = accz[i];
        }
      }
      __syncthreads();
      if (kh == 0){
        #pragma unroll
        for (int i = 0; i < 4; ++i){
          int row = rA + lq*4 + i;
          float pr = accr[i] + partial[mt][lane][i]   + bf2f((unsigned short)xr[i]);
          float pz = accz[i] + partial[mt][lane][4+i] + bf2f((unsigned short)xz[i]);
          float rg = 1.f / (1.f + __expf(-pr));
          float zg = 1.f / (1.f + __expf(-pz));
          zloc[row][lr] = zg;
          float av = hloc[row][lr] * rg;
          unsigned short hi = f2bf(av);
          unsigned short lo = f2bf(av - bf2f(hi));
          unsigned hi2 = (unsigned)__shfl_down((int)hi, 1) & 0xffffu;
          unsigned lo2 = (unsigned)__shfl_down((int)lo, 1) & 0xffffu;
          if (!(lane & 1)){
            cstore_u32(&abhi[row*1024 + 16*b + lr], (unsigned)hi | (hi2<<16));
            cstore_u32(&ablo[row*1024 + 16*b + lr], (unsigned)lo | (lo2<<16));
          }
        }
      }
    }
    gbar(bar, &bk);
    // ================= phase B: cand + state update =================
    {
      __builtin_amdgcn_fence(__ATOMIC_ACQUIRE, "agent");
      const float* xc_t = XprojC + (size_t)t*Bz*1024;
      float xcv[4];
      #pragma unroll
      for (int i = 0; i < 4; ++i)
        PLOADF(xcv[i], &xc_t[(rA + lq*4 + i)*1024 + 16*b + lr]);
      const unsigned short* ahp = abhi + (rA + lr)*1024 + kb + lq*8;
      const unsigned short* alp = ablo + (rA + lr)*1024 + kb + lq*8;
      u32x4 ahv[8], alv[8];
      #pragma unroll
      for (int s = 0; s < 8; ++s){ PLOAD16(ahv[s], ahp, s) PLOAD16(alv[s], alp, s) }
      f32x4 acc0={0,0,0,0}, acc1={0,0,0,0};
      #pragma unroll
      for (int k = 0; k < 16; ++k){
        const int slot = k & 7;
        VMWAIT(k < 8 ? 14 : 30 - 2*k)
        short8 ah = __builtin_bit_cast(short8, ahv[slot]);
        short8 al = __builtin_bit_cast(short8, alv[slot]);
        short8 bb = *reinterpret_cast<const short8*>(
            &WhhS[(lr*1024 + kb + k*32 + lq*8) ^ ((lr&7)<<3)]);
        acc0 = __builtin_amdgcn_mfma_f32_16x16x32_bf16(ah, bb, acc0, 0,0,0);
        acc1 = __builtin_amdgcn_mfma_f32_16x16x32_bf16(al, bb, acc1, 0,0,0);
        if (k < 8){ PLOAD16(ahv[slot], ahp, k+8) PLOAD16(alv[slot], alp, k+8) }
      }
      f32x4 acc = acc0 + acc1;
      if (kh == 1){
        #pragma unroll
        for (int i = 0; i < 4; ++i) partial[mt][lane][i] = acc[i];
      }
      __syncthreads();
      if (kh == 0){
        #pragma unroll
        for (int i = 0; i < 4; ++i){
          int row = rA + lq*4 + i;
          int col = 16*b + lr;
          float pre = acc[i] + partial[mt][lane][i] + xcv[i];
          float cand = tanhf(pre);
          float zg = zloc[row][lr];
          float h  = hloc[row][lr];
          float hnew = zg*h + (1.f - zg)*cand;
          hloc[row][lr] = hnew;
          unsigned short hi = f2bf(hnew);
          unsigned short lo = f2bf(hnew - bf2f(hi));
          unsigned hi2 = (unsigned)__shfl_down((int)hi, 1) & 0xffffu;
          unsigned lo2 = (unsigned)__shfl_down((int)lo, 1) & 0xffffu;
          float hnew2 = __shfl_down(hnew, 1);
          if (!(lane & 1)){
            cstore_u32(&hhi[row*1024 + col], (unsigned)hi | (hi2<<16));
            cstore_u32(&hlo[row*1024 + col], (unsigned)lo | (lo2<<16));
            if (h0seq) cstore_u32(&h0seq[(size_t)t*(Bz*Hh) + row*1024 + col],
                                  (unsigned)hi | (hi2<<16));
            if (outseq){
              cstore_f32(&outseq[(size_t)t*(Bz*Hh) + row*1024 + col],     hnew);
              cstore_f32(&outseq[(size_t)t*(Bz*Hh) + row*1024 + col + 1], hnew2);
            }
            if (t == Tt-1){
              cstore_f32(&hn[row*1024 + col],     hnew);
              cstore_f32(&hn[row*1024 + col + 1], hnew2);
            }
          }
        }
      }
    }
    gbar(bar, &bk);
  }
}

// ---------------- host ----------------

extern "C" void kernel_launch(void* const* d_in, const int* in_sizes, int n_in,
                              void* d_out, int out_size, void* d_ws, size_t ws_size,
                              hipStream_t stream)
{
  (void)in_sizes; (void)n_in; (void)out_size; (void)ws_size;
  const float* X     = (const float*)d_in[0];
  const float* Wxrz0 = (const float*)d_in[1];
  const float* bxrz0 = (const float*)d_in[2];
  const float* Whrz0 = (const float*)d_in[3];
  const float* bhrz0 = (const float*)d_in[4];
  const float* Wxh0  = (const float*)d_in[5];
  const float* bxh0  = (const float*)d_in[6];
  const float* Whh0  = (const float*)d_in[7];
  const float* bhh0  = (const float*)d_in[8];
  const float* Wxrz1 = (const float*)d_in[9];
  const float* bxrz1 = (const float*)d_in[10];
  const float* Whrz1 = (const float*)d_in[11];
  const float* bhrz1 = (const float*)d_in[12];
  const float* Wxh1  = (const float*)d_in[13];
  const float* bxh1  = (const float*)d_in[14];
  const float* Whh1  = (const float*)d_in[15];
  const float* bhh1  = (const float*)d_in[16];

  char* p = (char*)d_ws;
  auto carve = [&](size_t bytes)->char*{
    char* r = p; p += (bytes + 255) & ~(size_t)255; return r;
  };
  unsigned short* Xbf    = (unsigned short*)carve((size_t)Mrows*512*2);
  unsigned short* W0t    = (unsigned short*)carve((size_t)3072*512*2);
  unsigned short* W1t    = (unsigned short*)carve((size_t)3072*1024*2);
  unsigned short* Whrz0t = (unsigned short*)carve((size_t)2048*1024*2);
  unsigned short* Whh0t  = (unsigned short*)carve((size_t)1024*1024*2);
  unsigned short* Whrz1t = (unsigned short*)carve((size_t)2048*1024*2);
  unsigned short* Whh1t  = (unsigned short*)carve((size_t)1024*1024*2);
  float* bias0 = (float*)carve(3072*4);
  float* bias1 = (float*)carve(3072*4);
  unsigned short* XprojRZ = (unsigned short*)carve((size_t)Mrows*2048*2);
  float*          XprojC  = (float*)carve((size_t)Mrows*1024*4);
  unsigned short* H0seq   = (unsigned short*)carve((size_t)Mrows*1024*2);
  unsigned short* hhi  = (unsigned short*)carve(Bz*Hh*2);
  unsigned short* hlo  = (unsigned short*)carve(Bz*Hh*2);
  unsigned short* abhi = (unsigned short*)carve(Bz*Hh*2);
  unsigned short* ablo = (unsigned short*)carve(Bz*Hh*2);
  unsigned* bar = (unsigned*)carve(512);

  hipMemsetAsync(bar, 0, 512, stream);

  k_cvt_bf16<<<2048,256,0,stream>>>(X, Xbf, Mrows*512/4);
  k_transpose_bf16<<<dim3(8,32), 256,0,stream>>>(Wxrz0, W0t, 512, 2048);
  k_transpose_bf16<<<dim3(8,16), 256,0,stream>>>(Wxh0,  W0t + (size_t)2048*512, 512, 1024);
  k_transpose_bf16<<<dim3(16,32),256,0,stream>>>(Whrz0, Whrz0t, 1024, 2048);
  k_transpose_bf16<<<dim3(16,16),256,0,stream>>>(Whh0,  Whh0t, 1024, 1024);
  k_transpose_bf16<<<dim3(16,32),256,0,stream>>>(Wxrz1, W1t, 1024, 2048);
  k_transpose_bf16<<<dim3(16,16),256,0,stream>>>(Wxh1,  W1t + (size_t)2048*1024, 1024, 1024);
  k_transpose_bf16<<<dim3(16,32),256,0,stream>>>(Whrz1, Whrz1t, 1024, 2048);
  k_transpose_bf16<<<dim3(16,16),256,0,stream>>>(Whh1,  Whh1t, 1024, 1024);
  k_bias_fold<<<12,256,0,stream>>>(bxrz0, bhrz0, bxh0, bhh0, bias0);
  k_bias_fold<<<12,256,0,stream>>>(bxrz1, bhrz1, bxh1, bhh1, bias1);

  float* out = (float*)d_out;
  float* hn0 = out + (size_t)Mrows*Hh;
  float* hn1 = hn0 + Bz*Hh;

  // ---- layer 0 ----
  k_xproj_gemm<<<dim3(24,256),256,0,stream>>>(Xbf, W0t, bias0, XprojRZ, XprojC, 512);
  k_gru_layer<<<NBLK,512,0,stream>>>(Whrz0t, Whh0t, XprojRZ, XprojC,
                                     hhi, hlo, abhi, ablo,
                                     H0seq, nullptr, hn0, bar);
  // ---- layer 1 ----
  k_xproj_gemm<<<dim3(24,256),256,0,stream>>>(H0seq, W1t, bias1, XprojRZ, XprojC, 1024);
  k_gru_layer<<<NBLK,512,0,stream>>>(Whrz1t, Whh1t, XprojRZ, XprojC,
                                     hhi, hlo, abhi, ablo,
                                     nullptr, out, hn1, bar + 64);
}

// Round 8
// 15584.987 us; speedup vs baseline: 2.7439x; 1.7870x over previous
//
#include <hip/hip_runtime.h>
#include <hip/hip_bf16.h>

// GRU: T=512, B=64, Cin=512, H=1024, 2 layers.
// Round 8: BATCH-SPLIT persistent kernel on 256 CUs. Rounds 5-7 established
// step_time = coherent_bytes_per_CU / 25GB/s (per-CU cap, not fabric). Batch
// rows are independent -> grid = 4 batch-groups x 64 col-groups = 256 blocks;
// each block reads only its 16 rows of h/a (128KB/CU/step vs r5's 512KB).
// Same 2 barriers/step; K reduced inside the block across 8 waves via LDS.

#define Hh   1024
#define Bz   64
#define Tt   512
#define Mrows (Tt*Bz)   // 32768
#define NBLK 256

typedef __attribute__((ext_vector_type(8))) short short8;
typedef __attribute__((ext_vector_type(4))) float f32x4;
typedef __attribute__((ext_vector_type(4))) unsigned int u32x4;
typedef unsigned long long u64;

__device__ __forceinline__ unsigned short f2bf(float f){
  unsigned u = __builtin_bit_cast(unsigned, f);
  u += 0x7fffu + ((u >> 16) & 1u);          // round-to-nearest-even
  return (unsigned short)(u >> 16);
}
__device__ __forceinline__ float bf2f(unsigned short s){
  unsigned u = ((unsigned)s) << 16;
  return __builtin_bit_cast(float, u);
}

// write-through coherent stores (agent scope, relaxed)
__device__ __forceinline__ void cstore_u32(void* p, unsigned v){
  __hip_atomic_store((unsigned*)p, v, __ATOMIC_RELAXED, __HIP_MEMORY_SCOPE_AGENT);
}
__device__ __forceinline__ void cstore_u64(void* p, u64 v){
  __hip_atomic_store((u64*)p, v, __ATOMIC_RELAXED, __HIP_MEMORY_SCOPE_AGENT);
}

__device__ __forceinline__ void gload16(const void* g, void* l){
  __builtin_amdgcn_global_load_lds(
      (const __attribute__((address_space(1))) unsigned int*)g,
      (__attribute__((address_space(3))) unsigned int*)l, 16, 0, 0);
}

// fence-free device barrier: monotonic counter, no reset.
__device__ __forceinline__ void gbar(unsigned* bar, unsigned* bk){
  __syncthreads();
  *bk += 1;
  if (threadIdx.x == 0){
    __hip_atomic_fetch_add(bar, 1u, __ATOMIC_RELAXED, __HIP_MEMORY_SCOPE_AGENT);
    const unsigned tgt = (*bk) * NBLK;
    while (__hip_atomic_load(bar, __ATOMIC_RELAXED, __HIP_MEMORY_SCOPE_AGENT) < tgt)
      __builtin_amdgcn_s_sleep(1);
  }
  __syncthreads();
}

// ---- pipelined loads ----
#define CLOAD16(dst, base, kk) \
  asm volatile("global_load_dwordx4 %0, %1, off offset:%c2 sc0 sc1" \
               : "=v"(dst) : "v"(base), "i"((kk)*64));
#define PLOADF(dst, addr) \
  asm volatile("global_load_dword %0, %1, off" : "=v"(dst) : "v"(addr));
#define PLOADU16(dst, addr) \
  asm volatile("global_load_ushort %0, %1, off" : "=v"(dst) : "v"(addr));
#define VMWAIT(n) \
  asm volatile("s_waitcnt vmcnt(%c0)" :: "i"(n) : "memory"); \
  __builtin_amdgcn_sched_barrier(0);

// ---------------- prep kernels ----------------

__global__ __launch_bounds__(256) void k_cvt_bf16(const float* __restrict__ src,
                                                  unsigned short* __restrict__ dst, int n4){
  int i = blockIdx.x*blockDim.x + threadIdx.x;
  int stride = gridDim.x*blockDim.x;
  for (; i < n4; i += stride){
    float4 v = reinterpret_cast<const float4*>(src)[i];
    ushort4 o; o.x=f2bf(v.x); o.y=f2bf(v.y); o.z=f2bf(v.z); o.w=f2bf(v.w);
    reinterpret_cast<ushort4*>(dst)[i] = o;
  }
}

// fp32 (K,N) -> bf16 (N,K), 64x64 LDS tile
__global__ __launch_bounds__(256) void k_transpose_bf16(const float* __restrict__ src,
                                                        unsigned short* __restrict__ dst,
                                                        int K, int N){
  __shared__ float tile[64][65];
  int k0 = blockIdx.x * 64, n0 = blockIdx.y * 64;
  int t = threadIdx.x;
  int r = t >> 4, c4 = (t & 15) << 2;
  #pragma unroll
  for (int j = 0; j < 4; ++j){
    const float4 v = *reinterpret_cast<const float4*>(&src[(size_t)(k0 + r + j*16) * N + n0 + c4]);
    tile[r+j*16][c4+0]=v.x; tile[r+j*16][c4+1]=v.y;
    tile[r+j*16][c4+2]=v.z; tile[r+j*16][c4+3]=v.w;
  }
  __syncthreads();
  #pragma unroll
  for (int j = 0; j < 4; ++j){
    int nn = r + j*16;
    ushort4 o;
    o.x = f2bf(tile[c4+0][nn]); o.y = f2bf(tile[c4+1][nn]);
    o.z = f2bf(tile[c4+2][nn]); o.w = f2bf(tile[c4+3][nn]);
    *reinterpret_cast<ushort4*>(&dst[(size_t)(n0+nn)*K + k0 + c4]) = o;
  }
}

__global__ void k_bias_fold(const float* __restrict__ a, const float* __restrict__ b,
                            const float* __restrict__ c, const float* __restrict__ d,
                            float* __restrict__ out){
  int i = blockIdx.x*blockDim.x + threadIdx.x;
  if (i < 2048) out[i] = a[i] + b[i];
  else if (i < 3072) out[i] = c[i-2048] + d[i-2048];
}

// ---------------- big x-projection GEMM ----------------
__global__ __launch_bounds__(256) void k_xproj_gemm(
    const unsigned short* __restrict__ A, const unsigned short* __restrict__ Bt,
    const float* __restrict__ bias, unsigned short* __restrict__ outRZ,
    float* __restrict__ outC, int K)
{
  __shared__ __align__(16) unsigned short As[128*32];
  __shared__ __align__(16) unsigned short Bs[128*32];
  const int nb = blockIdx.x, mb = blockIdx.y;
  const int m0 = mb*128, n0 = nb*128;
  const int t = threadIdx.x, lane = t & 63, w = t >> 6;
  const int wr = w >> 1, wc = w & 1;
  const int lr = lane & 15, lq = lane >> 4;
  const int sr = t >> 2, scg = t & 3;
  f32x4 acc[4][4];
  const f32x4 zero4 = {0.f,0.f,0.f,0.f};
  #pragma unroll
  for (int mt=0;mt<4;++mt)
    #pragma unroll
    for (int nt=0;nt<4;++nt) acc[mt][nt] = zero4;

  const unsigned short* ga0 = &A [(size_t)(m0 + sr     )*K + scg*8];
  const unsigned short* ga1 = &A [(size_t)(m0 + sr + 64)*K + scg*8];
  const unsigned short* gb0 = &Bt[(size_t)(n0 + sr     )*K + scg*8];
  const unsigned short* gb1 = &Bt[(size_t)(n0 + sr + 64)*K + scg*8];
  char* lA = (char*)As + w*1024;
  char* lB = (char*)Bs + w*1024;
  const int kiters = K >> 5;
  for (int kt = 0; kt < kiters; ++kt){
    __syncthreads();
    gload16(ga0 + kt*32, lA);
    gload16(ga1 + kt*32, lA + 4096);
    gload16(gb0 + kt*32, lB);
    gload16(gb1 + kt*32, lB + 4096);
    asm volatile("s_waitcnt vmcnt(0)" ::: "memory");
    __syncthreads();
    short8 af[4], bfr[4];
    #pragma unroll
    for (int mt=0; mt<4; ++mt)
      af[mt] = *reinterpret_cast<const short8*>(&As[(wr*64 + mt*16 + lr)*32 + lq*8]);
    #pragma unroll
    for (int nt=0; nt<4; ++nt)
      bfr[nt] = *reinterpret_cast<const short8*>(&Bs[(wc*64 + nt*16 + lr)*32 + lq*8]);
    #pragma unroll
    for (int mt=0; mt<4; ++mt)
      #pragma unroll
      for (int nt=0; nt<4; ++nt)
        acc[mt][nt] = __builtin_amdgcn_mfma_f32_16x16x32_bf16(af[mt], bfr[nt], acc[mt][nt], 0,0,0);
  }
  const bool isRZ = (n0 < 2048);
  #pragma unroll
  for (int mt=0;mt<4;++mt){
    #pragma unroll
    for (int nt=0;nt<4;++nt){
      int gn = n0 + wc*64 + nt*16 + lr;
      float bv = bias[gn];
      #pragma unroll
      for (int i=0;i<4;++i){
        int gm = m0 + wr*64 + mt*16 + lq*4 + i;
        float v = acc[mt][nt][i] + bv;
        if (isRZ) outRZ[(size_t)gm*2048 + gn] = f2bf(v);
        else      outC [(size_t)gm*1024 + (gn - 2048)] = v;
      }
    }
  }
}

// ---------------- persistent per-layer recurrent kernel ----------------
// 256 blocks x 512 threads (1 block/CU, full chip). Block (g,c):
// owns batch rows [16g,16g+16) x cols [16c,16c+16) of r/z/cand/h.
// 8 waves = K-slices of 128; K reduced in LDS. 2 global barriers/step.
__global__ __launch_bounds__(512) void k_gru_layer(
    const unsigned short* __restrict__ Wrzg,   // (2048,1024) bf16
    const unsigned short* __restrict__ Whhg,   // (1024,1024) bf16
    const unsigned short* __restrict__ XprojRZ,// (T,64,2048) bf16, biases folded
    const float* __restrict__ XprojC,          // (T,64,1024) fp32, biases folded
    unsigned short* hhi, unsigned short* hlo,
    unsigned short* abhi, unsigned short* ablo,
    unsigned short* __restrict__ h0seq,        // L0: bf16 sequence out (else null)
    float* __restrict__ outseq,                // L1: fp32 sequence out (else null)
    float* __restrict__ hn,                    // final h slot
    unsigned* bar)
{
  __shared__ __align__(16) unsigned short WrzS[32*1024]; // 64KB rows0-15=r,16-31=z
  __shared__ __align__(16) unsigned short WhhS[16*1024]; // 32KB
  __shared__ float hloc[16][17];                         // block's fp32 h tile
  __shared__ float zloc[16][17];                         // block's z tile
  __shared__ float part[8][64][9];                       // 8-wave K-combine

  const int bid = blockIdx.x;
  const int g = bid & 3;          // batch group (rows 16g..16g+16)
  const int c = bid >> 2;         // column group (cols 16c..16c+16)
  const int tid = threadIdx.x;
  const int lane = tid & 63, w = tid >> 6;
  const int lr = lane & 15, lq = lane >> 4;
  unsigned bk = 0;

  // ---- stage weights into LDS (once), XOR-swizzled ----
  #pragma unroll
  for (int j = 0; j < 8; ++j){
    int lin = (tid + j*512) * 8;
    int n = lin >> 10, k = lin & 1023;
    int gr = (n < 16) ? (16*c + n) : (1024 + 16*c + (n - 16));
    short8 v = *reinterpret_cast<const short8*>(&Wrzg[(size_t)gr*1024 + k]);
    *reinterpret_cast<short8*>(&WrzS[(n*1024 + k) ^ ((n&7)<<3)]) = v;
  }
  #pragma unroll
  for (int j = 0; j < 4; ++j){
    int lin = (tid + j*512) * 8;
    int n = lin >> 10, k = lin & 1023;
    short8 v = *reinterpret_cast<const short8*>(&Whhg[(size_t)(16*c + n)*1024 + k]);
    *reinterpret_cast<short8*>(&WhhS[(n*1024 + k) ^ ((n&7)<<3)]) = v;
  }
  // ---- zero local h tile and global h slice (ws is poisoned) ----
  for (int idx = tid; idx < 16*17; idx += 512) ((float*)hloc)[idx] = 0.f;
  if (tid < 128){
    int r = tid >> 3, cp = (tid & 7) * 2;
    cstore_u32(&hhi[(16*g + r)*1024 + 16*c + cp], 0u);
    cstore_u32(&hlo[(16*g + r)*1024 + 16*c + cp], 0u);
  }
  gbar(bar, &bk);

  const int kb = 128 * w;   // this wave's K-slice

  for (int t = 0; t < Tt; ++t){
    // ================= phase A: rz preact + gates =================
    {
      const unsigned short* xp = XprojRZ + (size_t)t*Bz*2048;
      // wave 0: r-col xproj scalars; wave 1: z-col (issued FIRST for vmcnt parity)
      unsigned xv[4];
      if (w == 0){
        #pragma unroll
        for (int i = 0; i < 4; ++i)
          PLOADU16(xv[i], &xp[(16*g + lq*4 + i)*2048 + 16*c + lr]);
      } else if (w == 1){
        #pragma unroll
        for (int i = 0; i < 4; ++i)
          PLOADU16(xv[i], &xp[(16*g + lq*4 + i)*2048 + 1024 + 16*c + lr]);
      }
      const unsigned short* hhp = hhi + (size_t)(16*g + lr)*1024 + kb + lq*8;
      const unsigned short* hlp = hlo + (size_t)(16*g + lr)*1024 + kb + lq*8;
      u32x4 ahv[4], alv[4];
      #pragma unroll
      for (int s = 0; s < 4; ++s){ CLOAD16(ahv[s], hhp, s) CLOAD16(alv[s], hlp, s) }
      f32x4 accr0={0,0,0,0}, accr1={0,0,0,0}, accz0={0,0,0,0}, accz1={0,0,0,0};
      #pragma unroll
      for (int k = 0; k < 4; ++k){
        VMWAIT(6 - 2*k)   // same closed form for all waves (extra scalars lead)
        short8 ah = __builtin_bit_cast(short8, ahv[k]);
        short8 al = __builtin_bit_cast(short8, alv[k]);
        short8 br = *reinterpret_cast<const short8*>(
            &WrzS[(lr*1024 + kb + k*32 + lq*8) ^ ((lr&7)<<3)]);
        short8 bz = *reinterpret_cast<const short8*>(
            &WrzS[((16+lr)*1024 + kb + k*32 + lq*8) ^ ((lr&7)<<3)]);
        accr0 = __builtin_amdgcn_mfma_f32_16x16x32_bf16(ah, br, accr0, 0,0,0);
        accr1 = __builtin_amdgcn_mfma_f32_16x16x32_bf16(al, br, accr1, 0,0,0);
        accz0 = __builtin_amdgcn_mfma_f32_16x16x32_bf16(ah, bz, accz0, 0,0,0);
        accz1 = __builtin_amdgcn_mfma_f32_16x16x32_bf16(al, bz, accz1, 0,0,0);
      }
      #pragma unroll
      for (int i = 0; i < 4; ++i){
        part[w][lane][i]   = accr0[i] + accr1[i];
        part[w][lane][4+i] = accz0[i] + accz1[i];
      }
      __syncthreads();
      if (w == 0){          // r-gate + a = h*r
        #pragma unroll
        for (int i = 0; i < 4; ++i){
          float s_ = 0.f;
          #pragma unroll
          for (int ww = 0; ww < 8; ++ww) s_ += part[ww][lane][i];
          int row = lq*4 + i;
          float pr = s_ + bf2f((unsigned short)xv[i]);
          float rg = 1.f / (1.f + __expf(-pr));
          float av = hloc[row][lr] * rg;
          unsigned short hi = f2bf(av);
          unsigned short lo = f2bf(av - bf2f(hi));
          unsigned hi2 = (unsigned)__shfl_down((int)hi, 1) & 0xffffu;
          unsigned lo2 = (unsigned)__shfl_down((int)lo, 1) & 0xffffu;
          if (!(lane & 1)){
            cstore_u32(&abhi[(16*g + row)*1024 + 16*c + lr], (unsigned)hi | (hi2<<16));
            cstore_u32(&ablo[(16*g + row)*1024 + 16*c + lr], (unsigned)lo | (lo2<<16));
          }
        }
      } else if (w == 1){   // z-gate
        #pragma unroll
        for (int i = 0; i < 4; ++i){
          float s_ = 0.f;
          #pragma unroll
          for (int ww = 0; ww < 8; ++ww) s_ += part[ww][lane][4+i];
          int row = lq*4 + i;
          float pz = s_ + bf2f((unsigned short)xv[i]);
          zloc[row][lr] = 1.f / (1.f + __expf(-pz));
        }
      }
    }
    gbar(bar, &bk);
    // ================= phase B: cand + state update =================
    {
      const float* xc = XprojC + (size_t)t*Bz*1024;
      float xcv[4];
      if (w == 0){
        #pragma unroll
        for (int i = 0; i < 4; ++i)
          PLOADF(xcv[i], &xc[(16*g + lq*4 + i)*1024 + 16*c + lr]);
      }
      const unsigned short* ahp = abhi + (size_t)(16*g + lr)*1024 + kb + lq*8;
      const unsigned short* alp = ablo + (size_t)(16*g + lr)*1024 + kb + lq*8;
      u32x4 ahv[4], alv[4];
      #pragma unroll
      for (int s = 0; s < 4; ++s){ CLOAD16(ahv[s], ahp, s) CLOAD16(alv[s], alp, s) }
      f32x4 acc0={0,0,0,0}, acc1={0,0,0,0};
      #pragma unroll
      for (int k = 0; k < 4; ++k){
        VMWAIT(6 - 2*k)
        short8 ah = __builtin_bit_cast(short8, ahv[k]);
        short8 al = __builtin_bit_cast(short8, alv[k]);
        short8 bb = *reinterpret_cast<const short8*>(
            &WhhS[(lr*1024 + kb + k*32 + lq*8) ^ ((lr&7)<<3)]);
        acc0 = __builtin_amdgcn_mfma_f32_16x16x32_bf16(ah, bb, acc0, 0,0,0);
        acc1 = __builtin_amdgcn_mfma_f32_16x16x32_bf16(al, bb, acc1, 0,0,0);
      }
      #pragma unroll
      for (int i = 0; i < 4; ++i) part[w][lane][i] = acc0[i] + acc1[i];
      __syncthreads();
      if (w == 0){
        #pragma unroll
        for (int i = 0; i < 4; ++i){
          float s_ = 0.f;
          #pragma unroll
          for (int ww = 0; ww < 8; ++ww) s_ += part[ww][lane][i];
          int row = lq*4 + i;
          int grow = 16*g + row, gcol = 16*c + lr;
          float pre = s_ + xcv[i];
          float cand = tanhf(pre);
          float zg = zloc[row][lr];
          float h  = hloc[row][lr];
          float hnew = zg*h + (1.f - zg)*cand;
          hloc[row][lr] = hnew;
          unsigned short hi = f2bf(hnew);
          unsigned short lo = f2bf(hnew - bf2f(hi));
          unsigned hi2 = (unsigned)__shfl_down((int)hi, 1) & 0xffffu;
          unsigned lo2 = (unsigned)__shfl_down((int)lo, 1) & 0xffffu;
          float hnew2 = __shfl_down(hnew, 1);
          if (!(lane & 1)){
            cstore_u32(&hhi[(size_t)grow*1024 + gcol], (unsigned)hi | (hi2<<16));
            cstore_u32(&hlo[(size_t)grow*1024 + gcol], (unsigned)lo | (lo2<<16));
            if (h0seq)
              cstore_u32(&h0seq[(size_t)t*(Bz*Hh) + grow*1024 + gcol],
                         (unsigned)hi | (hi2<<16));
            if (outseq){
              float2 pr2 = {hnew, hnew2};
              cstore_u64(&outseq[(size_t)t*(Bz*Hh) + grow*1024 + gcol],
                         __builtin_bit_cast(u64, pr2));
            }
            if (t == Tt-1){
              float2 pr2 = {hnew, hnew2};
              cstore_u64(&hn[(size_t)grow*1024 + gcol], __builtin_bit_cast(u64, pr2));
            }
          }
        }
      }
    }
    gbar(bar, &bk);
  }
}

// ---------------- host ----------------

extern "C" void kernel_launch(void* const* d_in, const int* in_sizes, int n_in,
                              void* d_out, int out_size, void* d_ws, size_t ws_size,
                              hipStream_t stream)
{
  (void)in_sizes; (void)n_in; (void)out_size; (void)ws_size;
  const float* X     = (const float*)d_in[0];
  const float* Wxrz0 = (const float*)d_in[1];
  const float* bxrz0 = (const float*)d_in[2];
  const float* Whrz0 = (const float*)d_in[3];
  const float* bhrz0 = (const float*)d_in[4];
  const float* Wxh0  = (const float*)d_in[5];
  const float* bxh0  = (const float*)d_in[6];
  const float* Whh0  = (const float*)d_in[7];
  const float* bhh0  = (const float*)d_in[8];
  const float* Wxrz1 = (const float*)d_in[9];
  const float* bxrz1 = (const float*)d_in[10];
  const float* Whrz1 = (const float*)d_in[11];
  const float* bhrz1 = (const float*)d_in[12];
  const float* Wxh1  = (const float*)d_in[13];
  const float* bxh1  = (const float*)d_in[14];
  const float* Whh1  = (const float*)d_in[15];
  const float* bhh1  = (const float*)d_in[16];

  char* p = (char*)d_ws;
  auto carve = [&](size_t bytes)->char*{
    char* r = p; p += (bytes + 255) & ~(size_t)255; return r;
  };
  unsigned short* Xbf    = (unsigned short*)carve((size_t)Mrows*512*2);
  unsigned short* W0t    = (unsigned short*)carve((size_t)3072*512*2);
  unsigned short* W1t    = (unsigned short*)carve((size_t)3072*1024*2);
  unsigned short* Whrz0t = (unsigned short*)carve((size_t)2048*1024*2);
  unsigned short* Whh0t  = (unsigned short*)carve((size_t)1024*1024*2);
  unsigned short* Whrz1t = (unsigned short*)carve((size_t)2048*1024*2);
  unsigned short* Whh1t  = (unsigned short*)carve((size_t)1024*1024*2);
  float* bias0 = (float*)carve(3072*4);
  float* bias1 = (float*)carve(3072*4);
  unsigned short* XprojRZ = (unsigned short*)carve((size_t)Mrows*2048*2);
  float*          XprojC  = (float*)carve((size_t)Mrows*1024*4);
  unsigned short* H0seq   = (unsigned short*)carve((size_t)Mrows*1024*2);
  unsigned short* hhi  = (unsigned short*)carve(Bz*Hh*2);
  unsigned short* hlo  = (unsigned short*)carve(Bz*Hh*2);
  unsigned short* abhi = (unsigned short*)carve(Bz*Hh*2);
  unsigned short* ablo = (unsigned short*)carve(Bz*Hh*2);
  unsigned* bar = (unsigned*)carve(512);

  hipMemsetAsync(bar, 0, 512, stream);

  k_cvt_bf16<<<2048,256,0,stream>>>(X, Xbf, Mrows*512/4);
  k_transpose_bf16<<<dim3(8,32), 256,0,stream>>>(Wxrz0, W0t, 512, 2048);
  k_transpose_bf16<<<dim3(8,16), 256,0,stream>>>(Wxh0,  W0t + (size_t)2048*512, 512, 1024);
  k_transpose_bf16<<<dim3(16,32),256,0,stream>>>(Whrz0, Whrz0t, 1024, 2048);
  k_transpose_bf16<<<dim3(16,16),256,0,stream>>>(Whh0,  Whh0t, 1024, 1024);
  k_transpose_bf16<<<dim3(16,32),256,0,stream>>>(Wxrz1, W1t, 1024, 2048);
  k_transpose_bf16<<<dim3(16,16),256,0,stream>>>(Wxh1,  W1t + (size_t)2048*1024, 1024, 1024);
  k_transpose_bf16<<<dim3(16,32),256,0,stream>>>(Whrz1, Whrz1t, 1024, 2048);
  k_transpose_bf16<<<dim3(16,16),256,0,stream>>>(Whh1,  Whh1t, 1024, 1024);
  k_bias_fold<<<12,256,0,stream>>>(bxrz0, bhrz0, bxh0, bhh0, bias0);
  k_bias_fold<<<12,256,0,stream>>>(bxrz1, bhrz1, bxh1, bhh1, bias1);

  float* out = (float*)d_out;
  float* hn0 = out + (size_t)Mrows*Hh;
  float* hn1 = hn0 + Bz*Hh;

  // ---- layer 0 ----
  k_xproj_gemm<<<dim3(24,256),256,0,stream>>>(Xbf, W0t, bias0, XprojRZ, XprojC, 512);
  k_gru_layer<<<NBLK,512,0,stream>>>(Whrz0t, Whh0t, XprojRZ, XprojC,
                                     hhi, hlo, abhi, ablo,
                                     H0seq, nullptr, hn0, bar);
  // ---- layer 1 ----
  k_xproj_gemm<<<dim3(24,256),256,0,stream>>>(H0seq, W1t, bias1, XprojRZ, XprojC, 1024);
  k_gru_layer<<<NBLK,512,0,stream>>>(Whrz1t, Whh1t, XprojRZ, XprojC,
                                     hhi, hlo, abhi, ablo,
                                     nullptr, out, hn1, bar + 64);
}

// Round 9
// 9842.677 us; speedup vs baseline: 4.3447x; 1.5834x over previous
//
#include <hip/hip_runtime.h>
#include <hip/hip_bf16.h>

// GRU: T=512, B=64, Cin=512, H=1024, 2 layers.
// Round 9: per-batch-group barriers. Round 8 (256 blocks, batch-split) showed
// step = 5.2us traffic + ~10us of 256-arrival barrier serialization. All
// cross-block traffic stays within a batch-group (16 rows), so sync only the
// 64 blocks of each group: 4 independent counters on separate cachelines.

#define Hh   1024
#define Bz   64
#define Tt   512
#define Mrows (Tt*Bz)   // 32768
#define GBLK 64         // blocks per batch-group barrier

typedef __attribute__((ext_vector_type(8))) short short8;
typedef __attribute__((ext_vector_type(4))) float f32x4;
typedef __attribute__((ext_vector_type(4))) unsigned int u32x4;
typedef unsigned long long u64;

__device__ __forceinline__ unsigned short f2bf(float f){
  unsigned u = __builtin_bit_cast(unsigned, f);
  u += 0x7fffu + ((u >> 16) & 1u);          // round-to-nearest-even
  return (unsigned short)(u >> 16);
}
__device__ __forceinline__ float bf2f(unsigned short s){
  unsigned u = ((unsigned)s) << 16;
  return __builtin_bit_cast(float, u);
}

// write-through coherent stores (agent scope, relaxed)
__device__ __forceinline__ void cstore_u32(void* p, unsigned v){
  __hip_atomic_store((unsigned*)p, v, __ATOMIC_RELAXED, __HIP_MEMORY_SCOPE_AGENT);
}
__device__ __forceinline__ void cstore_u64(void* p, u64 v){
  __hip_atomic_store((u64*)p, v, __ATOMIC_RELAXED, __HIP_MEMORY_SCOPE_AGENT);
}

__device__ __forceinline__ void gload16(const void* g, void* l){
  __builtin_amdgcn_global_load_lds(
      (const __attribute__((address_space(1))) unsigned int*)g,
      (__attribute__((address_space(3))) unsigned int*)l, 16, 0, 0);
}

// fence-free GROUP barrier (64 arrivals): monotonic counter, no reset.
__device__ __forceinline__ void gbar(unsigned* ctr, unsigned* bk){
  __syncthreads();
  *bk += 1;
  if (threadIdx.x == 0){
    __hip_atomic_fetch_add(ctr, 1u, __ATOMIC_RELAXED, __HIP_MEMORY_SCOPE_AGENT);
    const unsigned tgt = (*bk) * GBLK;
    while (__hip_atomic_load(ctr, __ATOMIC_RELAXED, __HIP_MEMORY_SCOPE_AGENT) < tgt)
      __builtin_amdgcn_s_sleep(1);
  }
  __syncthreads();
}

// ---- pipelined loads ----
#define CLOAD16(dst, base, kk) \
  asm volatile("global_load_dwordx4 %0, %1, off offset:%c2 sc0 sc1" \
               : "=v"(dst) : "v"(base), "i"((kk)*64));
#define PLOADF(dst, addr) \
  asm volatile("global_load_dword %0, %1, off" : "=v"(dst) : "v"(addr));
#define PLOADU16(dst, addr) \
  asm volatile("global_load_ushort %0, %1, off" : "=v"(dst) : "v"(addr));
#define VMWAIT(n) \
  asm volatile("s_waitcnt vmcnt(%c0)" :: "i"(n) : "memory"); \
  __builtin_amdgcn_sched_barrier(0);

// ---------------- prep kernels ----------------

__global__ __launch_bounds__(256) void k_cvt_bf16(const float* __restrict__ src,
                                                  unsigned short* __restrict__ dst, int n4){
  int i = blockIdx.x*blockDim.x + threadIdx.x;
  int stride = gridDim.x*blockDim.x;
  for (; i < n4; i += stride){
    float4 v = reinterpret_cast<const float4*>(src)[i];
    ushort4 o; o.x=f2bf(v.x); o.y=f2bf(v.y); o.z=f2bf(v.z); o.w=f2bf(v.w);
    reinterpret_cast<ushort4*>(dst)[i] = o;
  }
}

// fp32 (K,N) -> bf16 (N,K), 64x64 LDS tile
__global__ __launch_bounds__(256) void k_transpose_bf16(const float* __restrict__ src,
                                                        unsigned short* __restrict__ dst,
                                                        int K, int N){
  __shared__ float tile[64][65];
  int k0 = blockIdx.x * 64, n0 = blockIdx.y * 64;
  int t = threadIdx.x;
  int r = t >> 4, c4 = (t & 15) << 2;
  #pragma unroll
  for (int j = 0; j < 4; ++j){
    const float4 v = *reinterpret_cast<const float4*>(&src[(size_t)(k0 + r + j*16) * N + n0 + c4]);
    tile[r+j*16][c4+0]=v.x; tile[r+j*16][c4+1]=v.y;
    tile[r+j*16][c4+2]=v.z; tile[r+j*16][c4+3]=v.w;
  }
  __syncthreads();
  #pragma unroll
  for (int j = 0; j < 4; ++j){
    int nn = r + j*16;
    ushort4 o;
    o.x = f2bf(tile[c4+0][nn]); o.y = f2bf(tile[c4+1][nn]);
    o.z = f2bf(tile[c4+2][nn]); o.w = f2bf(tile[c4+3][nn]);
    *reinterpret_cast<ushort4*>(&dst[(size_t)(n0+nn)*K + k0 + c4]) = o;
  }
}

__global__ void k_bias_fold(const float* __restrict__ a, const float* __restrict__ b,
                            const float* __restrict__ c, const float* __restrict__ d,
                            float* __restrict__ out){
  int i = blockIdx.x*blockDim.x + threadIdx.x;
  if (i < 2048) out[i] = a[i] + b[i];
  else if (i < 3072) out[i] = c[i-2048] + d[i-2048];
}

// ---------------- big x-projection GEMM ----------------
__global__ __launch_bounds__(256) void k_xproj_gemm(
    const unsigned short* __restrict__ A, const unsigned short* __restrict__ Bt,
    const float* __restrict__ bias, unsigned short* __restrict__ outRZ,
    float* __restrict__ outC, int K)
{
  __shared__ __align__(16) unsigned short As[128*32];
  __shared__ __align__(16) unsigned short Bs[128*32];
  const int nb = blockIdx.x, mb = blockIdx.y;
  const int m0 = mb*128, n0 = nb*128;
  const int t = threadIdx.x, lane = t & 63, w = t >> 6;
  const int wr = w >> 1, wc = w & 1;
  const int lr = lane & 15, lq = lane >> 4;
  const int sr = t >> 2, scg = t & 3;
  f32x4 acc[4][4];
  const f32x4 zero4 = {0.f,0.f,0.f,0.f};
  #pragma unroll
  for (int mt=0;mt<4;++mt)
    #pragma unroll
    for (int nt=0;nt<4;++nt) acc[mt][nt] = zero4;

  const unsigned short* ga0 = &A [(size_t)(m0 + sr     )*K + scg*8];
  const unsigned short* ga1 = &A [(size_t)(m0 + sr + 64)*K + scg*8];
  const unsigned short* gb0 = &Bt[(size_t)(n0 + sr     )*K + scg*8];
  const unsigned short* gb1 = &Bt[(size_t)(n0 + sr + 64)*K + scg*8];
  char* lA = (char*)As + w*1024;
  char* lB = (char*)Bs + w*1024;
  const int kiters = K >> 5;
  for (int kt = 0; kt < kiters; ++kt){
    __syncthreads();
    gload16(ga0 + kt*32, lA);
    gload16(ga1 + kt*32, lA + 4096);
    gload16(gb0 + kt*32, lB);
    gload16(gb1 + kt*32, lB + 4096);
    asm volatile("s_waitcnt vmcnt(0)" ::: "memory");
    __syncthreads();
    short8 af[4], bfr[4];
    #pragma unroll
    for (int mt=0; mt<4; ++mt)
      af[mt] = *reinterpret_cast<const short8*>(&As[(wr*64 + mt*16 + lr)*32 + lq*8]);
    #pragma unroll
    for (int nt=0; nt<4; ++nt)
      bfr[nt] = *reinterpret_cast<const short8*>(&Bs[(wc*64 + nt*16 + lr)*32 + lq*8]);
    #pragma unroll
    for (int mt=0; mt<4; ++mt)
      #pragma unroll
      for (int nt=0; nt<4; ++nt)
        acc[mt][nt] = __builtin_amdgcn_mfma_f32_16x16x32_bf16(af[mt], bfr[nt], acc[mt][nt], 0,0,0);
  }
  const bool isRZ = (n0 < 2048);
  #pragma unroll
  for (int mt=0;mt<4;++mt){
    #pragma unroll
    for (int nt=0;nt<4;++nt){
      int gn = n0 + wc*64 + nt*16 + lr;
      float bv = bias[gn];
      #pragma unroll
      for (int i=0;i<4;++i){
        int gm = m0 + wr*64 + mt*16 + lq*4 + i;
        float v = acc[mt][nt][i] + bv;
        if (isRZ) outRZ[(size_t)gm*2048 + gn] = f2bf(v);
        else      outC [(size_t)gm*1024 + (gn - 2048)] = v;
      }
    }
  }
}

// ---------------- persistent per-layer recurrent kernel ----------------
// 256 blocks x 512 threads (1 block/CU). Block (g,c): batch rows
// [16g,16g+16) x cols [16c,16c+16). All cross-block exchange stays inside
// group g -> per-group 64-arrival barrier. 8 waves = K-slices of 128.
__global__ __launch_bounds__(512) void k_gru_layer(
    const unsigned short* __restrict__ Wrzg,   // (2048,1024) bf16
    const unsigned short* __restrict__ Whhg,   // (1024,1024) bf16
    const unsigned short* __restrict__ XprojRZ,// (T,64,2048) bf16, biases folded
    const float* __restrict__ XprojC,          // (T,64,1024) fp32, biases folded
    unsigned short* hhi, unsigned short* hlo,
    unsigned short* abhi, unsigned short* ablo,
    unsigned short* __restrict__ h0seq,        // L0: bf16 sequence out (else null)
    float* __restrict__ outseq,                // L1: fp32 sequence out (else null)
    float* __restrict__ hn,                    // final h slot
    unsigned* bar)                             // 4 counters, 256B apart
{
  __shared__ __align__(16) unsigned short WrzS[32*1024]; // 64KB rows0-15=r,16-31=z
  __shared__ __align__(16) unsigned short WhhS[16*1024]; // 32KB
  __shared__ float hloc[16][17];                         // block's fp32 h tile
  __shared__ float zloc[16][17];                         // block's z tile
  __shared__ float part[8][64][9];                       // 8-wave K-combine

  const int bid = blockIdx.x;
  const int g = bid & 3;          // batch group (rows 16g..16g+16)
  const int c = bid >> 2;         // column group (cols 16c..16c+16)
  const int tid = threadIdx.x;
  const int lane = tid & 63, w = tid >> 6;
  const int lr = lane & 15, lq = lane >> 4;
  unsigned* ctr = bar + g*64;     // this group's counter (own cacheline)
  unsigned bk = 0;

  // ---- stage weights into LDS (once), XOR-swizzled ----
  #pragma unroll
  for (int j = 0; j < 8; ++j){
    int lin = (tid + j*512) * 8;
    int n = lin >> 10, k = lin & 1023;
    int gr = (n < 16) ? (16*c + n) : (1024 + 16*c + (n - 16));
    short8 v = *reinterpret_cast<const short8*>(&Wrzg[(size_t)gr*1024 + k]);
    *reinterpret_cast<short8*>(&WrzS[(n*1024 + k) ^ ((n&7)<<3)]) = v;
  }
  #pragma unroll
  for (int j = 0; j < 4; ++j){
    int lin = (tid + j*512) * 8;
    int n = lin >> 10, k = lin & 1023;
    short8 v = *reinterpret_cast<const short8*>(&Whhg[(size_t)(16*c + n)*1024 + k]);
    *reinterpret_cast<short8*>(&WhhS[(n*1024 + k) ^ ((n&7)<<3)]) = v;
  }
  // ---- zero local h tile and global h slice (ws is poisoned) ----
  for (int idx = tid; idx < 16*17; idx += 512) ((float*)hloc)[idx] = 0.f;
  if (tid < 128){
    int r = tid >> 3, cp = (tid & 7) * 2;
    cstore_u32(&hhi[(16*g + r)*1024 + 16*c + cp], 0u);
    cstore_u32(&hlo[(16*g + r)*1024 + 16*c + cp], 0u);
  }
  gbar(ctr, &bk);

  const int kb = 128 * w;   // this wave's K-slice

  for (int t = 0; t < Tt; ++t){
    // ================= phase A: rz preact + gates =================
    {
      const unsigned short* xp = XprojRZ + (size_t)t*Bz*2048;
      // wave 0: r-col xproj scalars; wave 1: z-col (issued FIRST for vmcnt parity)
      unsigned xv[4];
      if (w == 0){
        #pragma unroll
        for (int i = 0; i < 4; ++i)
          PLOADU16(xv[i], &xp[(16*g + lq*4 + i)*2048 + 16*c + lr]);
      } else if (w == 1){
        #pragma unroll
        for (int i = 0; i < 4; ++i)
          PLOADU16(xv[i], &xp[(16*g + lq*4 + i)*2048 + 1024 + 16*c + lr]);
      }
      const unsigned short* hhp = hhi + (size_t)(16*g + lr)*1024 + kb + lq*8;
      const unsigned short* hlp = hlo + (size_t)(16*g + lr)*1024 + kb + lq*8;
      u32x4 ahv[4], alv[4];
      #pragma unroll
      for (int s = 0; s < 4; ++s){ CLOAD16(ahv[s], hhp, s) CLOAD16(alv[s], hlp, s) }
      f32x4 accr0={0,0,0,0}, accr1={0,0,0,0}, accz0={0,0,0,0}, accz1={0,0,0,0};
      #pragma unroll
      for (int k = 0; k < 4; ++k){
        VMWAIT(6 - 2*k)   // same closed form for all waves (extra scalars lead)
        short8 ah = __builtin_bit_cast(short8, ahv[k]);
        short8 al = __builtin_bit_cast(short8, alv[k]);
        short8 br = *reinterpret_cast<const short8*>(
            &WrzS[(lr*1024 + kb + k*32 + lq*8) ^ ((lr&7)<<3)]);
        short8 bz = *reinterpret_cast<const short8*>(
            &WrzS[((16+lr)*1024 + kb + k*32 + lq*8) ^ ((lr&7)<<3)]);
        accr0 = __builtin_amdgcn_mfma_f32_16x16x32_bf16(ah, br, accr0, 0,0,0);
        accr1 = __builtin_amdgcn_mfma_f32_16x16x32_bf16(al, br, accr1, 0,0,0);
        accz0 = __builtin_amdgcn_mfma_f32_16x16x32_bf16(ah, bz, accz0, 0,0,0);
        accz1 = __builtin_amdgcn_mfma_f32_16x16x32_bf16(al, bz, accz1, 0,0,0);
      }
      #pragma unroll
      for (int i = 0; i < 4; ++i){
        part[w][lane][i]   = accr0[i] + accr1[i];
        part[w][lane][4+i] = accz0[i] + accz1[i];
      }
      __syncthreads();
      if (w == 0){          // r-gate + a = h*r
        #pragma unroll
        for (int i = 0; i < 4; ++i){
          float s_ = 0.f;
          #pragma unroll
          for (int ww = 0; ww < 8; ++ww) s_ += part[ww][lane][i];
          int row = lq*4 + i;
          float pr = s_ + bf2f((unsigned short)xv[i]);
          float rg = 1.f / (1.f + __expf(-pr));
          float av = hloc[row][lr] * rg;
          unsigned short hi = f2bf(av);
          unsigned short lo = f2bf(av - bf2f(hi));
          unsigned hi2 = (unsigned)__shfl_down((int)hi, 1) & 0xffffu;
          unsigned lo2 = (unsigned)__shfl_down((int)lo, 1) & 0xffffu;
          if (!(lane & 1)){
            cstore_u32(&abhi[(16*g + row)*1024 + 16*c + lr], (unsigned)hi | (hi2<<16));
            cstore_u32(&ablo[(16*g + row)*1024 + 16*c + lr], (unsigned)lo | (lo2<<16));
          }
        }
      } else if (w == 1){   // z-gate
        #pragma unroll
        for (int i = 0; i < 4; ++i){
          float s_ = 0.f;
          #pragma unroll
          for (int ww = 0; ww < 8; ++ww) s_ += part[ww][lane][4+i];
          int row = lq*4 + i;
          float pz = s_ + bf2f((unsigned short)xv[i]);
          zloc[row][lr] = 1.f / (1.f + __expf(-pz));
        }
      }
    }
    gbar(ctr, &bk);
    // ================= phase B: cand + state update =================
    {
      const float* xc = XprojC + (size_t)t*Bz*1024;
      float xcv[4];
      if (w == 0){
        #pragma unroll
        for (int i = 0; i < 4; ++i)
          PLOADF(xcv[i], &xc[(16*g + lq*4 + i)*1024 + 16*c + lr]);
      }
      const unsigned short* ahp = abhi + (size_t)(16*g + lr)*1024 + kb + lq*8;
      const unsigned short* alp = ablo + (size_t)(16*g + lr)*1024 + kb + lq*8;
      u32x4 ahv[4], alv[4];
      #pragma unroll
      for (int s = 0; s < 4; ++s){ CLOAD16(ahv[s], ahp, s) CLOAD16(alv[s], alp, s) }
      f32x4 acc0={0,0,0,0}, acc1={0,0,0,0};
      #pragma unroll
      for (int k = 0; k < 4; ++k){
        VMWAIT(6 - 2*k)
        short8 ah = __builtin_bit_cast(short8, ahv[k]);
        short8 al = __builtin_bit_cast(short8, alv[k]);
        short8 bb = *reinterpret_cast<const short8*>(
            &WhhS[(lr*1024 + kb + k*32 + lq*8) ^ ((lr&7)<<3)]);
        acc0 = __builtin_amdgcn_mfma_f32_16x16x32_bf16(ah, bb, acc0, 0,0,0);
        acc1 = __builtin_amdgcn_mfma_f32_16x16x32_bf16(al, bb, acc1, 0,0,0);
      }
      #pragma unroll
      for (int i = 0; i < 4; ++i) part[w][lane][i] = acc0[i] + acc1[i];
      __syncthreads();
      if (w == 0){
        #pragma unroll
        for (int i = 0; i < 4; ++i){
          float s_ = 0.f;
          #pragma unroll
          for (int ww = 0; ww < 8; ++ww) s_ += part[ww][lane][i];
          int row = lq*4 + i;
          int grow = 16*g + row, gcol = 16*c + lr;
          float pre = s_ + xcv[i];
          float cand = tanhf(pre);
          float zg = zloc[row][lr];
          float h  = hloc[row][lr];
          float hnew = zg*h + (1.f - zg)*cand;
          hloc[row][lr] = hnew;
          unsigned short hi = f2bf(hnew);
          unsigned short lo = f2bf(hnew - bf2f(hi));
          unsigned hi2 = (unsigned)__shfl_down((int)hi, 1) & 0xffffu;
          unsigned lo2 = (unsigned)__shfl_down((int)lo, 1) & 0xffffu;
          float hnew2 = __shfl_down(hnew, 1);
          if (!(lane & 1)){
            cstore_u32(&hhi[(size_t)grow*1024 + gcol], (unsigned)hi | (hi2<<16));
            cstore_u32(&hlo[(size_t)grow*1024 + gcol], (unsigned)lo | (lo2<<16));
            if (h0seq)
              cstore_u32(&h0seq[(size_t)t*(Bz*Hh) + grow*1024 + gcol],
                         (unsigned)hi | (hi2<<16));
            if (outseq){
              float2 pr2 = {hnew, hnew2};
              cstore_u64(&outseq[(size_t)t*(Bz*Hh) + grow*1024 + gcol],
                         __builtin_bit_cast(u64, pr2));
            }
            if (t == Tt-1){
              float2 pr2 = {hnew, hnew2};
              cstore_u64(&hn[(size_t)grow*1024 + gcol], __builtin_bit_cast(u64, pr2));
            }
          }
        }
      }
    }
    gbar(ctr, &bk);
  }
}

// ---------------- host ----------------

extern "C" void kernel_launch(void* const* d_in, const int* in_sizes, int n_in,
                              void* d_out, int out_size, void* d_ws, size_t ws_size,
                              hipStream_t stream)
{
  (void)in_sizes; (void)n_in; (void)out_size; (void)ws_size;
  const float* X     = (const float*)d_in[0];
  const float* Wxrz0 = (const float*)d_in[1];
  const float* bxrz0 = (const float*)d_in[2];
  const float* Whrz0 = (const float*)d_in[3];
  const float* bhrz0 = (const float*)d_in[4];
  const float* Wxh0  = (const float*)d_in[5];
  const float* bxh0  = (const float*)d_in[6];
  const float* Whh0  = (const float*)d_in[7];
  const float* bhh0  = (const float*)d_in[8];
  const float* Wxrz1 = (const float*)d_in[9];
  const float* bxrz1 = (const float*)d_in[10];
  const float* Whrz1 = (const float*)d_in[11];
  const float* bhrz1 = (const float*)d_in[12];
  const float* Wxh1  = (const float*)d_in[13];
  const float* bxh1  = (const float*)d_in[14];
  const float* Whh1  = (const float*)d_in[15];
  const float* bhh1  = (const float*)d_in[16];

  char* p = (char*)d_ws;
  auto carve = [&](size_t bytes)->char*{
    char* r = p; p += (bytes + 255) & ~(size_t)255; return r;
  };
  unsigned short* Xbf    = (unsigned short*)carve((size_t)Mrows*512*2);
  unsigned short* W0t    = (unsigned short*)carve((size_t)3072*512*2);
  unsigned short* W1t    = (unsigned short*)carve((size_t)3072*1024*2);
  unsigned short* Whrz0t = (unsigned short*)carve((size_t)2048*1024*2);
  unsigned short* Whh0t  = (unsigned short*)carve((size_t)1024*1024*2);
  unsigned short* Whrz1t = (unsigned short*)carve((size_t)2048*1024*2);
  unsigned short* Whh1t  = (unsigned short*)carve((size_t)1024*1024*2);
  float* bias0 = (float*)carve(3072*4);
  float* bias1 = (float*)carve(3072*4);
  unsigned short* XprojRZ = (unsigned short*)carve((size_t)Mrows*2048*2);
  float*          XprojC  = (float*)carve((size_t)Mrows*1024*4);
  unsigned short* H0seq   = (unsigned short*)carve((size_t)Mrows*1024*2);
  unsigned short* hhi  = (unsigned short*)carve(Bz*Hh*2);
  unsigned short* hlo  = (unsigned short*)carve(Bz*Hh*2);
  unsigned short* abhi = (unsigned short*)carve(Bz*Hh*2);
  unsigned short* ablo = (unsigned short*)carve(Bz*Hh*2);
  unsigned* bar = (unsigned*)carve(2048);   // L0: 4 counters @256B; L1: +1024B

  hipMemsetAsync(bar, 0, 2048, stream);

  k_cvt_bf16<<<2048,256,0,stream>>>(X, Xbf, Mrows*512/4);
  k_transpose_bf16<<<dim3(8,32), 256,0,stream>>>(Wxrz0, W0t, 512, 2048);
  k_transpose_bf16<<<dim3(8,16), 256,0,stream>>>(Wxh0,  W0t + (size_t)2048*512, 512, 1024);
  k_transpose_bf16<<<dim3(16,32),256,0,stream>>>(Whrz0, Whrz0t, 1024, 2048);
  k_transpose_bf16<<<dim3(16,16),256,0,stream>>>(Whh0,  Whh0t, 1024, 1024);
  k_transpose_bf16<<<dim3(16,32),256,0,stream>>>(Wxrz1, W1t, 1024, 2048);
  k_transpose_bf16<<<dim3(16,16),256,0,stream>>>(Wxh1,  W1t + (size_t)2048*1024, 1024, 1024);
  k_transpose_bf16<<<dim3(16,32),256,0,stream>>>(Whrz1, Whrz1t, 1024, 2048);
  k_transpose_bf16<<<dim3(16,16),256,0,stream>>>(Whh1,  Whh1t, 1024, 1024);
  k_bias_fold<<<12,256,0,stream>>>(bxrz0, bhrz0, bxh0, bhh0, bias0);
  k_bias_fold<<<12,256,0,stream>>>(bxrz1, bhrz1, bxh1, bhh1, bias1);

  float* out = (float*)d_out;
  float* hn0 = out + (size_t)Mrows*Hh;
  float* hn1 = hn0 + Bz*Hh;

  // ---- layer 0 ----
  k_xproj_gemm<<<dim3(24,256),256,0,stream>>>(Xbf, W0t, bias0, XprojRZ, XprojC, 512);
  k_gru_layer<<<256,512,0,stream>>>(Whrz0t, Whh0t, XprojRZ, XprojC,
                                    hhi, hlo, abhi, ablo,
                                    H0seq, nullptr, hn0, bar);
  // ---- layer 1 ----
  k_xproj_gemm<<<dim3(24,256),256,0,stream>>>(H0seq, W1t, bias1, XprojRZ, XprojC, 1024);
  k_gru_layer<<<256,512,0,stream>>>(Whrz1t, Whh1t, XprojRZ, XprojC,
                                    hhi, hlo, abhi, ablo,
                                    nullptr, out, hn1, bar + 256);
}